// Round 10
// baseline (757.915 us; speedup 1.0000x reference)
//
#include <hip/hip_runtime.h>
#include <hip/hip_bf16.h>
#include <math.h>

#define NN 10000
#define EE 80000
#define SDIM 18
#define HID 1024
#define NLAYERS 4
#define GHID 256

typedef __bf16 bf16;
typedef __bf16 bf16x8 __attribute__((ext_vector_type(8)));
typedef __bf16 bf16x4 __attribute__((ext_vector_type(4)));
typedef float f32x4 __attribute__((ext_vector_type(4)));
typedef unsigned int u32x4 __attribute__((ext_vector_type(4)));  // clang vector: OK for nontemporal builtins

#define AS1C(p) ((const __attribute__((address_space(1))) void*)(p))
#define AS3(p)  ((__attribute__((address_space(3))) void*)(p))

// ---------------- CSR build: count ----------------
__global__ void count_kernel(const int* __restrict__ ei, int* __restrict__ cnt) {
    int e = blockIdx.x * 256 + threadIdx.x;
    if (e < EE) atomicAdd(&cnt[ei[EE + e]], 1);
}

// ---------------- CSR build: exclusive scan (single block) ----------------
__global__ __launch_bounds__(256) void scan_kernel(const int* __restrict__ cnt,
                                                   int* __restrict__ offs,
                                                   int* __restrict__ cursor,
                                                   float* __restrict__ degF) {
    const int CH = 40;  // 256*40 = 10240 >= NN
    __shared__ int partial[256];
    int t = threadIdx.x;
    int base = t * CH;
    int local[CH];
    int sum = 0;
#pragma unroll
    for (int i = 0; i < CH; ++i) {
        int idx = base + i;
        int v = (idx < NN) ? cnt[idx] : 0;
        local[i] = sum;
        sum += v;
    }
    partial[t] = sum;
    __syncthreads();
    for (int off = 1; off < 256; off <<= 1) {
        int v = (t >= off) ? partial[t - off] : 0;
        __syncthreads();
        partial[t] += v;
        __syncthreads();
    }
    int excl = (t == 0) ? 0 : partial[t - 1];
#pragma unroll
    for (int i = 0; i < CH; ++i) {
        int idx = base + i;
        if (idx < NN) {
            int o = excl + local[i];
            offs[idx] = o;
            cursor[idx] = o;
            degF[idx] = (float)cnt[idx];
        }
    }
    if (t == 255) offs[NN] = partial[255];
}

// ---------------- CSR build: scatter edge sources ----------------
__global__ void scatter_kernel(const int* __restrict__ ei, int* __restrict__ cursor,
                               int* __restrict__ esrc) {
    int e = blockIdx.x * 256 + threadIdx.x;
    if (e < EE) {
        int dst = ei[EE + e];
        int pos = atomicAdd(&cursor[dst], 1);
        esrc[pos] = ei[e];
    }
}

// ---------------- fused prep: all weight transposes + swt + cb + cnt-zero ----------------
__global__ __launch_bounds__(256) void prep_kernel(const float* __restrict__ W1,
                                                   const float* __restrict__ W2,
                                                   const float* __restrict__ gw1,
                                                   const float* __restrict__ sw,
                                                   const float* __restrict__ b1,
                                                   bf16* __restrict__ WT,
                                                   bf16* __restrict__ W2t,
                                                   bf16* __restrict__ gw1t,
                                                   bf16* __restrict__ swt,
                                                   float* __restrict__ cb,
                                                   int* __restrict__ cnt) {
    __shared__ float td[32][33];
    __shared__ float tb[32][33];
    const size_t H2 = (size_t)HID * HID;
    int b = blockIdx.x;
    int tx = threadIdx.x & 31, ty = threadIdx.x >> 5;  // (32,8)

    if (b < 4096) {  // W1 fused diff transpose
        int l = b >> 10, r = b & 1023;
        int bx = (r & 31) * 32, by = (r >> 5) * 32;
        const float* s = W1 + (size_t)l * 2 * H2;
        bf16* d = WT + (size_t)l * 2 * H2;
#pragma unroll
        for (int r4 = 0; r4 < 4; ++r4) {
            int row = by + ty + r4 * 8;
            float vt = s[(size_t)row * HID + bx + tx];
            float vb = s[H2 + (size_t)row * HID + bx + tx];
            td[ty + r4 * 8][tx] = vt - vb;
            tb[ty + r4 * 8][tx] = vb;
        }
        __syncthreads();
#pragma unroll
        for (int r4 = 0; r4 < 4; ++r4) {
            int orow = bx + ty + r4 * 8;
            d[(size_t)orow * HID + by + tx] = (bf16)td[tx][ty + r4 * 8];
            d[(size_t)(HID + orow) * HID + by + tx] = (bf16)tb[tx][ty + r4 * 8];
        }
    } else if (b < 8192) {  // W2 transpose
        int sub = b - 4096;
        int l = sub >> 10, r = sub & 1023;
        int bx = (r & 31) * 32, by = (r >> 5) * 32;
        const float* s = W2 + (size_t)l * H2;
        bf16* d = W2t + (size_t)l * H2;
#pragma unroll
        for (int r4 = 0; r4 < 4; ++r4) {
            int row = by + ty + r4 * 8;
            td[ty + r4 * 8][tx] = s[(size_t)row * HID + bx + tx];
        }
        __syncthreads();
#pragma unroll
        for (int r4 = 0; r4 < 4; ++r4) {
            int orow = bx + ty + r4 * 8;
            d[(size_t)orow * HID + by + tx] = (bf16)td[tx][ty + r4 * 8];
        }
    } else if (b < 8448) {  // gw1 [1024][256] -> gw1t [256][1024]
        int sub = b - 8192;
        int bx = (sub & 7) * 32, by = (sub >> 3) * 32;
#pragma unroll
        for (int r4 = 0; r4 < 4; ++r4) {
            int row = by + ty + r4 * 8;
            td[ty + r4 * 8][tx] = gw1[(size_t)row * GHID + bx + tx];
        }
        __syncthreads();
#pragma unroll
        for (int r4 = 0; r4 < 4; ++r4) {
            int orow = bx + ty + r4 * 8;
            gw1t[(size_t)orow * HID + by + tx] = (bf16)td[tx][ty + r4 * 8];
        }
    } else if (b < 8576) {  // swt[32][1024] = sw[1024][18]^T zero-padded
        int i = (b - 8448) * 256 + threadIdx.x;
        int n = i >> 10, k = i & 1023;
        swt[i] = (bf16)(n < SDIM ? sw[k * SDIM + n] : 0.f);
    } else if (b < 8608) {  // cb[l][2048] = [b1[l] ; 0]
        int i = (b - 8576) * 256 + threadIdx.x;
        int l = i >> 11, c = i & 2047;
        cb[i] = (c < HID) ? b1[l * HID + c] : 0.f;
    } else {  // cnt zero
        int i = (b - 8608) * 256 + threadIdx.x;
        if (i < NN) cnt[i] = 0;
    }
}

// ---------------- h0 = sin(x@pw)*cos(x@pw) -> bf16 ----------------
__global__ __launch_bounds__(256) void proj_kernel(const float* __restrict__ x,
                                                   const float* __restrict__ pw,
                                                   bf16* __restrict__ hb) {
    int row = blockIdx.y;
    int col = blockIdx.x * 256 + threadIdx.x;
    __shared__ float xr[SDIM];
    if (threadIdx.x < SDIM) xr[threadIdx.x] = x[row * SDIM + threadIdx.x];
    __syncthreads();
    float acc = 0.f;
#pragma unroll
    for (int k = 0; k < SDIM; ++k) acc += xr[k] * pw[k * HID + col];
    hb[(size_t)row * HID + col] = (bf16)(sinf(acc) * cosf(acc));
}

// ---------------- 256x128 BK=32 triple-buffered counted-vmcnt MFMA GEMM ----------------
// R5/R8-verified (57.5 us @ CB shape). 8 waves (4M x 2N), 512 threads.
// LDS 72 KiB -> 2 blocks/CU. vmcnt(3) counted waits, compile-time mod-3
// buffers, T2 seg-XOR both-sides swizzle, GROUP-8 block swizzle.
template <int RELU, int HAS_BIAS, int HAS_RS, int WF32, int WB16>
__global__ __launch_bounds__(512, 4) void mgemm3_kernel(const bf16* __restrict__ A,
                                                        const bf16* __restrict__ Bt,
                                                        float* __restrict__ C,
                                                        bf16* __restrict__ Cb,
                                                        const float* __restrict__ bias,
                                                        const float* __restrict__ rowscale,
                                                        int M, int N, int K) {
    __shared__ bf16 lds[36864];  // 72 KiB
    const int tid = threadIdx.x;
    const int wave = tid >> 6, lane = tid & 63;
    const int wm = wave >> 1, wn = wave & 1;  // 4M x 2N
    const int quad = lane >> 4, r15 = lane & 15;

    const int num_n = gridDim.x, num_m = gridDim.y;
    int bid = blockIdx.x + blockIdx.y * num_n;
    const int GROUP = 8;
    int width = GROUP * num_n;
    int group = bid / width;
    int rem = bid - group * width;
    int rows_ing = num_m - group * GROUP;
    rows_ing = rows_ing < GROUP ? rows_ing : GROUP;
    int by = group * GROUP + rem % rows_ing;
    int bx = rem / rows_ing;
    const int m0 = by * 256, n0 = bx * 128;

    const int strow = tid >> 2;  // 0..127
    const int segsw = ((tid & 3) ^ ((tid >> 3) & 3)) * 8;
    int ar0 = m0 + strow;        ar0 = ar0 < M ? ar0 : M - 1;
    int ar1 = m0 + 128 + strow;  ar1 = ar1 < M ? ar1 : M - 1;
    const bf16* ga0 = A + (size_t)ar0 * K + segsw;
    const bf16* ga1 = A + (size_t)ar1 * K + segsw;
    const bf16* gb  = Bt + (size_t)(n0 + strow) * K + segsw;
    const int ldst = (tid & ~63) * 8;

    int aoff[4], boff[4];
#pragma unroll
    for (int i = 0; i < 4; ++i) {
        int rA = wm * 64 + i * 16 + r15;
        aoff[i] = 12288 + rA * 32 + (quad ^ ((rA >> 1) & 3)) * 8;
        int rB = wn * 64 + i * 16 + r15;
        boff[i] = rB * 32 + (quad ^ ((rB >> 1) & 3)) * 8;
    }

    f32x4 acc[4][4] = {};

#define STAGE3(bs, kt)                                                                                \
    do {                                                                                              \
        const int ko_ = (kt) << 5;                                                                    \
        __builtin_amdgcn_global_load_lds(AS1C(ga0 + ko_), AS3(&lds[12288 + (bs)*8192 + ldst]), 16, 0, 0); \
        __builtin_amdgcn_global_load_lds(AS1C(ga1 + ko_), AS3(&lds[12288 + (bs)*8192 + 4096 + ldst]), 16, 0, 0); \
        __builtin_amdgcn_global_load_lds(AS1C(gb + ko_), AS3(&lds[(bs)*4096 + ldst]), 16, 0, 0);      \
    } while (0)

    STAGE3(0, 0);
    STAGE3(1, 1);
    asm volatile("s_waitcnt vmcnt(3)");
    __builtin_amdgcn_s_barrier();

    const int NT = K >> 5;
    int t = 0;

#define TILE3(bi, bs)                                                                          \
    do {                                                                                       \
        int kt = (t + 2 < NT) ? (t + 2) : (t - 1);                                             \
        bf16x8 aF[4], bF[4];                                                                   \
        _Pragma("unroll") for (int i = 0; i < 4; ++i)                                          \
            aF[i] = *(const bf16x8*)(&lds[(bi)*8192 + aoff[i]]);                               \
        _Pragma("unroll") for (int j = 0; j < 4; ++j)                                          \
            bF[j] = *(const bf16x8*)(&lds[(bi)*4096 + boff[j]]);                               \
        STAGE3(bs, kt);                                                                        \
        asm volatile("s_waitcnt lgkmcnt(0)");                                                  \
        __builtin_amdgcn_s_setprio(1);                                                         \
        _Pragma("unroll") for (int i = 0; i < 4; ++i)                                          \
            _Pragma("unroll") for (int j = 0; j < 4; ++j)                                      \
                acc[i][j] = __builtin_amdgcn_mfma_f32_16x16x32_bf16(aF[i], bF[j], acc[i][j], 0, 0, 0); \
        __builtin_amdgcn_s_setprio(0);                                                         \
        asm volatile("s_waitcnt vmcnt(3)");                                                    \
        __builtin_amdgcn_s_barrier();                                                          \
        ++t;                                                                                   \
    } while (0)

    while (t + 3 <= NT) { TILE3(0, 2); TILE3(1, 0); TILE3(2, 1); }
    if (t < NT) TILE3(0, 2);
    if (t < NT) TILE3(1, 0);
#undef TILE3
#undef STAGE3

#pragma unroll
    for (int i = 0; i < 4; ++i) {
#pragma unroll
        for (int r = 0; r < 4; ++r) {
            int grow = m0 + wm * 64 + i * 16 + quad * 4 + r;
            if (grow >= M) continue;
            float rs = HAS_RS ? rowscale[grow] : 1.f;
#pragma unroll
            for (int j = 0; j < 4; ++j) {
                int gcol = n0 + wn * 64 + j * 16 + r15;
                float v = acc[i][j][r];
                if (HAS_BIAS) v += rs * bias[gcol];
                if (RELU) v = fmaxf(v, 0.f);
                if (WF32) C[(size_t)grow * N + gcol] = v;
                if (WB16) Cb[(size_t)grow * N + gcol] = (bf16)v;
            }
        }
    }
}

// ---------------- 128x128 BK=32 triple-buffered counted-vmcnt MFMA GEMM ----------------
// R7-verified. 4 waves, 256 threads, LDS 48 KiB -> 3 blocks/CU. For W2/ghost
// (sub-single-wave regime where occupancy beats intensity).
template <int RELU, int HAS_BIAS, int HAS_RS, int WF32, int WB16>
__global__ __launch_bounds__(256, 3) void mgemm3h_kernel(const bf16* __restrict__ A,
                                                         const bf16* __restrict__ Bt,
                                                         float* __restrict__ C,
                                                         bf16* __restrict__ Cb,
                                                         const float* __restrict__ bias,
                                                         const float* __restrict__ rowscale,
                                                         int M, int N, int K) {
    __shared__ bf16 lds[24576];  // 48 KiB
    const int tid = threadIdx.x;
    const int wave = tid >> 6, lane = tid & 63;
    const int wm = wave >> 1, wn = wave & 1;  // 2M x 2N
    const int quad = lane >> 4, r15 = lane & 15;

    const int num_n = gridDim.x, num_m = gridDim.y;
    int bid = blockIdx.x + blockIdx.y * num_n;
    const int GROUP = 8;
    int width = GROUP * num_n;
    int group = bid / width;
    int rem = bid - group * width;
    int rows_ing = num_m - group * GROUP;
    rows_ing = rows_ing < GROUP ? rows_ing : GROUP;
    int by = group * GROUP + rem % rows_ing;
    int bx = rem / rows_ing;
    const int m0 = by * 128, n0 = bx * 128;

    const int strow = tid >> 2;  // 0..63
    const int segsw = ((tid & 3) ^ ((tid >> 3) & 3)) * 8;
    int ar0 = m0 + strow;       ar0 = ar0 < M ? ar0 : M - 1;
    int ar1 = m0 + 64 + strow;  ar1 = ar1 < M ? ar1 : M - 1;
    const bf16* ga0 = A + (size_t)ar0 * K + segsw;
    const bf16* ga1 = A + (size_t)ar1 * K + segsw;
    const bf16* gb0 = Bt + (size_t)(n0 + strow) * K + segsw;
    const bf16* gb1 = Bt + (size_t)(n0 + 64 + strow) * K + segsw;
    const int ldst = (tid & ~63) * 8;

    int aoff[4], boff[4];
#pragma unroll
    for (int i = 0; i < 4; ++i) {
        int rA = wm * 64 + i * 16 + r15;
        aoff[i] = 12288 + rA * 32 + (quad ^ ((rA >> 1) & 3)) * 8;
        int rB = wn * 64 + i * 16 + r15;
        boff[i] = rB * 32 + (quad ^ ((rB >> 1) & 3)) * 8;
    }

    f32x4 acc[4][4] = {};

#define STAGE3H(bs, kt)                                                                                  \
    do {                                                                                                 \
        const int ko_ = (kt) << 5;                                                                       \
        __builtin_amdgcn_global_load_lds(AS1C(ga0 + ko_), AS3(&lds[12288 + (bs)*4096 + ldst]), 16, 0, 0); \
        __builtin_amdgcn_global_load_lds(AS1C(ga1 + ko_), AS3(&lds[12288 + (bs)*4096 + 2048 + ldst]), 16, 0, 0); \
        __builtin_amdgcn_global_load_lds(AS1C(gb0 + ko_), AS3(&lds[(bs)*4096 + ldst]), 16, 0, 0);        \
        __builtin_amdgcn_global_load_lds(AS1C(gb1 + ko_), AS3(&lds[(bs)*4096 + 2048 + ldst]), 16, 0, 0); \
    } while (0)

    STAGE3H(0, 0);
    STAGE3H(1, 1);
    asm volatile("s_waitcnt vmcnt(4)");
    __builtin_amdgcn_s_barrier();

    const int NT = K >> 5;
    int t = 0;

#define TILE3H(bi, bs)                                                                         \
    do {                                                                                       \
        int kt = (t + 2 < NT) ? (t + 2) : (t - 1);                                             \
        bf16x8 aF[4], bF[4];                                                                   \
        _Pragma("unroll") for (int i = 0; i < 4; ++i)                                          \
            aF[i] = *(const bf16x8*)(&lds[(bi)*4096 + aoff[i]]);                               \
        _Pragma("unroll") for (int j = 0; j < 4; ++j)                                          \
            bF[j] = *(const bf16x8*)(&lds[(bi)*4096 + boff[j]]);                               \
        STAGE3H(bs, kt);                                                                       \
        asm volatile("s_waitcnt lgkmcnt(0)");                                                  \
        __builtin_amdgcn_s_setprio(1);                                                         \
        _Pragma("unroll") for (int i = 0; i < 4; ++i)                                          \
            _Pragma("unroll") for (int j = 0; j < 4; ++j)                                      \
                acc[i][j] = __builtin_amdgcn_mfma_f32_16x16x32_bf16(aF[i], bF[j], acc[i][j], 0, 0, 0); \
        __builtin_amdgcn_s_setprio(0);                                                         \
        asm volatile("s_waitcnt vmcnt(4)");                                                    \
        __builtin_amdgcn_s_barrier();                                                          \
        ++t;                                                                                   \
    } while (0)

    while (t + 3 <= NT) { TILE3H(0, 2); TILE3H(1, 0); TILE3H(2, 1); }
    if (t < NT) TILE3H(0, 2);
    if (t < NT) TILE3H(1, 0);
#undef TILE3H
#undef STAGE3H

#pragma unroll
    for (int i = 0; i < 4; ++i) {
#pragma unroll
        for (int r = 0; r < 4; ++r) {
            int grow = m0 + wm * 64 + i * 16 + quad * 4 + r;
            if (grow >= M) continue;
            float rs = HAS_RS ? rowscale[grow] : 1.f;
#pragma unroll
            for (int j = 0; j < 4; ++j) {
                int gcol = n0 + wn * 64 + j * 16 + r15;
                float v = acc[i][j][r];
                if (HAS_BIAS) v += rs * bias[gcol];
                if (RELU) v = fmaxf(v, 0.f);
                if (WF32) C[(size_t)grow * N + gcol] = v;
                if (WB16) Cb[(size_t)grow * N + gcol] = (bf16)v;
            }
        }
    }
}

// ---------------- XCD-chunked CSR aggregation over CB[node][2048] = [Cn ; Bn] ----------------
// Block (chunk=bid&7, grp=bid>>3): 16 nodes x 128 cols; 16 lanes/node x 8 cols.
// chunk->XCD affinity (consecutive bids round-robin XCDs): each chunk's Bn
// column-slab (10000 x 128 x 2B = 2.56 MB) fits one XCD's 4 MiB L2, so the
// ~8x edge reuse becomes L2 hits instead of 160 MB of L3/HBM row reads.
// Cn reads / Sb writes are nontemporal (streaming, no reuse) to keep the
// slab resident.
__global__ __launch_bounds__(256) void gather_kernel(const int* __restrict__ offs,
                                                     const int* __restrict__ esrc,
                                                     const bf16* __restrict__ CB,
                                                     bf16* __restrict__ Sb) {
    int chunk = blockIdx.x & 7, grp = blockIdx.x >> 3;
    int sub = threadIdx.x >> 4;      // node within group (0..15)
    int t = threadIdx.x & 15;        // col-lane (16 x 8 cols = 128)
    int node = grp * 16 + sub;       // 625*16 = 10000 exact
    int c = chunk * 128 + t * 8;
    int k0 = offs[node], k1 = offs[node + 1];
    u32x4 craw = __builtin_nontemporal_load((const u32x4*)(CB + (size_t)node * 2048 + c));
    bf16x8 cv = *(bf16x8*)&craw;
    float cf[8], a[8];
#pragma unroll
    for (int i = 0; i < 8; ++i) { cf[i] = (float)cv[i]; a[i] = 0.f; }
    for (int k = k0; k < k1; ++k) {
        int s = esrc[k];
        bf16x8 bv = *(const bf16x8*)(CB + (size_t)s * 2048 + 1024 + c);
#pragma unroll
        for (int i = 0; i < 8; ++i) a[i] += fmaxf(cf[i] + (float)bv[i], 0.f);
    }
    bf16x8 o;
#pragma unroll
    for (int i = 0; i < 8; ++i) o[i] = (bf16)a[i];
    __builtin_nontemporal_store(*(u32x4*)&o, (u32x4*)(Sb + (size_t)node * HID + c));
}

// ---------------- stable head via MFMA ----------------
__global__ __launch_bounds__(64) void stable_mfma_kernel(const bf16* __restrict__ hb,
                                                         const bf16* __restrict__ swt,
                                                         const float* __restrict__ sb,
                                                         float* __restrict__ out) {
    int m0 = blockIdx.x * 16;  // NN = 625*16 exact
    int lane = threadIdx.x;
    int quad = lane >> 4, r15 = lane & 15;
    f32x4 acc0 = {}, acc1 = {};
    const bf16* arow = hb + (size_t)(m0 + r15) * HID + quad * 8;
    const bf16* b0 = swt + (size_t)r15 * HID + quad * 8;
    const bf16* b1p = swt + (size_t)(16 + r15) * HID + quad * 8;
    for (int k0 = 0; k0 < HID; k0 += 32) {
        bf16x8 af = *(const bf16x8*)(arow + k0);
        bf16x8 bf0 = *(const bf16x8*)(b0 + k0);
        bf16x8 bf1 = *(const bf16x8*)(b1p + k0);
        acc0 = __builtin_amdgcn_mfma_f32_16x16x32_bf16(af, bf0, acc0, 0, 0, 0);
        acc1 = __builtin_amdgcn_mfma_f32_16x16x32_bf16(af, bf1, acc1, 0, 0, 0);
    }
#pragma unroll
    for (int r = 0; r < 4; ++r) {
        int grow = m0 + quad * 4 + r;
        out[(size_t)grow * SDIM + r15] = acc0[r] + sb[r15];
        if (r15 < 2) out[(size_t)grow * SDIM + 16 + r15] = acc1[r] + sb[16 + r15];
    }
}

// ---------------- ghost head stage 2 ----------------
__global__ __launch_bounds__(256) void ghost_kernel(const float* __restrict__ g1,
                                                    const float* __restrict__ gw2,
                                                    const float* __restrict__ gb2,
                                                    float* __restrict__ out) {
    int w = threadIdx.x >> 6, lane = threadIdx.x & 63;
    int row = blockIdx.x * 4 + w;  // NN = 2500*4 exact
    const float4 gv = *(const float4*)(g1 + (size_t)row * GHID + lane * 4);
    const float4 wv = *(const float4*)(gw2 + lane * 4);
    float v = gv.x * wv.x + gv.y * wv.y + gv.z * wv.z + gv.w * wv.w;
#pragma unroll
    for (int o = 32; o > 0; o >>= 1) v += __shfl_down(v, o, 64);
    if (lane == 0) out[row] = 1.f / (1.f + expf(-(v + gb2[0])));
}

extern "C" void kernel_launch(void* const* d_in, const int* in_sizes, int n_in,
                              void* d_out, int out_size, void* d_ws, size_t ws_size,
                              hipStream_t stream) {
    const float* x   = (const float*)d_in[0];
    const int*   ei  = (const int*)d_in[1];
    const float* pw  = (const float*)d_in[2];
    const float* W1  = (const float*)d_in[3];
    const float* b1  = (const float*)d_in[4];
    const float* W2  = (const float*)d_in[5];
    const float* b2  = (const float*)d_in[6];
    const float* gw1 = (const float*)d_in[7];
    const float* gb1 = (const float*)d_in[8];
    const float* gw2 = (const float*)d_in[9];
    const float* gb2 = (const float*)d_in[10];
    const float* sw  = (const float*)d_in[11];
    const float* sb  = (const float*)d_in[12];

    float* out    = (float*)d_out;
    float* ghost  = out;                  // [N,1]
    float* stable = out + NN;             // [N,18]
    float* h      = out + NN + NN * SDIM; // [N,HID] fp32 (final h output)

    const size_t H2 = (size_t)HID * HID;
    float* ws   = (float*)d_ws;
    float* g1   = ws;                                  // NN*GHID fp32
    float* degF = g1 + (size_t)NN * GHID;              // NN
    float* cb   = degF + NN;                           // 4*2048 fp32
    bf16* hb    = (bf16*)(cb + 4 * 2048);              // NN*HID
    bf16* Sb    = hb + (size_t)NN * HID;               // NN*HID
    bf16* CB    = Sb + (size_t)NN * HID;               // NN*2048
    bf16* WT    = CB + (size_t)NN * 2048;              // 4 * 2*H2  ([Wd;Wb]^T per layer)
    bf16* W2t   = WT + 8 * H2;                         // 4*H2
    bf16* gw1t  = W2t + 4 * H2;                        // GHID*HID
    bf16* swt   = gw1t + (size_t)GHID * HID;           // 32*1024
    int*  cnt    = (int*)(swt + 32 * 1024);
    int*  offs   = cnt + NN;
    int*  cursor = offs + NN + 1;
    int*  esrc   = cursor + NN;

    // ---- fused prep (weights transpose/convert + swt + cb + cnt zero) ----
    prep_kernel<<<dim3(8648), 256, 0, stream>>>(W1, W2, gw1, sw, b1, WT, W2t, gw1t, swt, cb, cnt);

    // ---- CSR build ----
    count_kernel<<<dim3((EE + 255) / 256), 256, 0, stream>>>(ei, cnt);
    scan_kernel<<<dim3(1), 256, 0, stream>>>(cnt, offs, cursor, degF);
    scatter_kernel<<<dim3((EE + 255) / 256), 256, 0, stream>>>(ei, cursor, esrc);

    // ---- h0 ----
    proj_kernel<<<dim3(HID / 256, NN), 256, 0, stream>>>(x, pw, hb);

    dim3 gcbg(2048 / 128, (NN + 255) / 256);     // (16, 40) = 640 blocks @ 256x128
    dim3 gw2grid(HID / 128, (NN + 127) / 128);   // (8, 79)  = 632 blocks @ 128x128
    for (int l = 0; l < NLAYERS; ++l) {
        // CB = hb @ [Wd ; Wb]^T + [b1 ; 0]   (N = 2048, fused Cn/Bn)
        mgemm3_kernel<0, 1, 0, 0, 1><<<gcbg, 512, 0, stream>>>(
            hb, WT + (size_t)l * 2 * H2, nullptr, CB, cb + l * 2048, nullptr, NN, 2048, HID);
        // S = segment_sum(relu(Cn[dst]+Bn[src])) — XCD-chunked
        gather_kernel<<<dim3((NN / 16) * 8), 256, 0, stream>>>(offs, esrc, CB, Sb);
        // h = relu(S @ W2 + deg*b2); last layer also writes fp32 h to d_out
        if (l < NLAYERS - 1)
            mgemm3h_kernel<1, 1, 1, 0, 1><<<gw2grid, 256, 0, stream>>>(
                Sb, W2t + (size_t)l * H2, nullptr, hb, b2 + (size_t)l * HID, degF, NN, HID, HID);
        else
            mgemm3h_kernel<1, 1, 1, 1, 1><<<gw2grid, 256, 0, stream>>>(
                Sb, W2t + (size_t)l * H2, h, hb, b2 + (size_t)l * HID, degF, NN, HID, HID);
    }

    // ---- ghost head (N=256, 158 blocks @ 128x128) ----
    mgemm3h_kernel<1, 1, 0, 1, 0><<<dim3(GHID / 128, (NN + 127) / 128), 256, 0, stream>>>(
        hb, gw1t, g1, nullptr, gb1, nullptr, NN, GHID, HID);
    ghost_kernel<<<dim3(NN / 4), 256, 0, stream>>>(g1, gw2, gb2, ghost);
    // ---- stable head (MFMA, 1 wave / 16 rows) ----
    stable_mfma_kernel<<<dim3(NN / 16), 64, 0, stream>>>(hb, swt, sb, stable);
}

// Round 11
// 689.727 us; speedup vs baseline: 1.0989x; 1.0989x over previous
//
#include <hip/hip_runtime.h>
#include <hip/hip_bf16.h>
#include <math.h>

#define NN 10000
#define EE 80000
#define SDIM 18
#define HID 1024
#define NLAYERS 4
#define GHID 256

typedef __bf16 bf16;
typedef __bf16 bf16x8 __attribute__((ext_vector_type(8)));
typedef __bf16 bf16x4 __attribute__((ext_vector_type(4)));
typedef float f32x4 __attribute__((ext_vector_type(4)));

#define AS1C(p) ((const __attribute__((address_space(1))) void*)(p))
#define AS3(p)  ((__attribute__((address_space(3))) void*)(p))

// ---------------- CSR build: count ----------------
__global__ void count_kernel(const int* __restrict__ ei, int* __restrict__ cnt) {
    int e = blockIdx.x * 256 + threadIdx.x;
    if (e < EE) atomicAdd(&cnt[ei[EE + e]], 1);
}

// ---------------- CSR build: exclusive scan (single block) ----------------
__global__ __launch_bounds__(256) void scan_kernel(const int* __restrict__ cnt,
                                                   int* __restrict__ offs,
                                                   int* __restrict__ cursor,
                                                   float* __restrict__ degF) {
    const int CH = 40;  // 256*40 = 10240 >= NN
    __shared__ int partial[256];
    int t = threadIdx.x;
    int base = t * CH;
    int local[CH];
    int sum = 0;
#pragma unroll
    for (int i = 0; i < CH; ++i) {
        int idx = base + i;
        int v = (idx < NN) ? cnt[idx] : 0;
        local[i] = sum;
        sum += v;
    }
    partial[t] = sum;
    __syncthreads();
    for (int off = 1; off < 256; off <<= 1) {
        int v = (t >= off) ? partial[t - off] : 0;
        __syncthreads();
        partial[t] += v;
        __syncthreads();
    }
    int excl = (t == 0) ? 0 : partial[t - 1];
#pragma unroll
    for (int i = 0; i < CH; ++i) {
        int idx = base + i;
        if (idx < NN) {
            int o = excl + local[i];
            offs[idx] = o;
            cursor[idx] = o;
            degF[idx] = (float)cnt[idx];
        }
    }
    if (t == 255) offs[NN] = partial[255];
}

// ---------------- CSR build: scatter edge sources ----------------
__global__ void scatter_kernel(const int* __restrict__ ei, int* __restrict__ cursor,
                               int* __restrict__ esrc) {
    int e = blockIdx.x * 256 + threadIdx.x;
    if (e < EE) {
        int dst = ei[EE + e];
        int pos = atomicAdd(&cursor[dst], 1);
        esrc[pos] = ei[e];
    }
}

// ---------------- fused prep: all weight transposes + swt + cb + cnt-zero ----------------
__global__ __launch_bounds__(256) void prep_kernel(const float* __restrict__ W1,
                                                   const float* __restrict__ W2,
                                                   const float* __restrict__ gw1,
                                                   const float* __restrict__ sw,
                                                   const float* __restrict__ b1,
                                                   bf16* __restrict__ WT,
                                                   bf16* __restrict__ W2t,
                                                   bf16* __restrict__ gw1t,
                                                   bf16* __restrict__ swt,
                                                   float* __restrict__ cb,
                                                   int* __restrict__ cnt) {
    __shared__ float td[32][33];
    __shared__ float tb[32][33];
    const size_t H2 = (size_t)HID * HID;
    int b = blockIdx.x;
    int tx = threadIdx.x & 31, ty = threadIdx.x >> 5;  // (32,8)

    if (b < 4096) {  // W1 fused diff transpose
        int l = b >> 10, r = b & 1023;
        int bx = (r & 31) * 32, by = (r >> 5) * 32;
        const float* s = W1 + (size_t)l * 2 * H2;
        bf16* d = WT + (size_t)l * 2 * H2;
#pragma unroll
        for (int r4 = 0; r4 < 4; ++r4) {
            int row = by + ty + r4 * 8;
            float vt = s[(size_t)row * HID + bx + tx];
            float vb = s[H2 + (size_t)row * HID + bx + tx];
            td[ty + r4 * 8][tx] = vt - vb;
            tb[ty + r4 * 8][tx] = vb;
        }
        __syncthreads();
#pragma unroll
        for (int r4 = 0; r4 < 4; ++r4) {
            int orow = bx + ty + r4 * 8;
            d[(size_t)orow * HID + by + tx] = (bf16)td[tx][ty + r4 * 8];
            d[(size_t)(HID + orow) * HID + by + tx] = (bf16)tb[tx][ty + r4 * 8];
        }
    } else if (b < 8192) {  // W2 transpose
        int sub = b - 4096;
        int l = sub >> 10, r = sub & 1023;
        int bx = (r & 31) * 32, by = (r >> 5) * 32;
        const float* s = W2 + (size_t)l * H2;
        bf16* d = W2t + (size_t)l * H2;
#pragma unroll
        for (int r4 = 0; r4 < 4; ++r4) {
            int row = by + ty + r4 * 8;
            td[ty + r4 * 8][tx] = s[(size_t)row * HID + bx + tx];
        }
        __syncthreads();
#pragma unroll
        for (int r4 = 0; r4 < 4; ++r4) {
            int orow = bx + ty + r4 * 8;
            d[(size_t)orow * HID + by + tx] = (bf16)td[tx][ty + r4 * 8];
        }
    } else if (b < 8448) {  // gw1 [1024][256] -> gw1t [256][1024]
        int sub = b - 8192;
        int bx = (sub & 7) * 32, by = (sub >> 3) * 32;
#pragma unroll
        for (int r4 = 0; r4 < 4; ++r4) {
            int row = by + ty + r4 * 8;
            td[ty + r4 * 8][tx] = gw1[(size_t)row * GHID + bx + tx];
        }
        __syncthreads();
#pragma unroll
        for (int r4 = 0; r4 < 4; ++r4) {
            int orow = bx + ty + r4 * 8;
            gw1t[(size_t)orow * HID + by + tx] = (bf16)td[tx][ty + r4 * 8];
        }
    } else if (b < 8576) {  // swt[32][1024] = sw[1024][18]^T zero-padded
        int i = (b - 8448) * 256 + threadIdx.x;
        int n = i >> 10, k = i & 1023;
        swt[i] = (bf16)(n < SDIM ? sw[k * SDIM + n] : 0.f);
    } else if (b < 8608) {  // cb[l][2048] = [b1[l] ; 0]
        int i = (b - 8576) * 256 + threadIdx.x;
        int l = i >> 11, c = i & 2047;
        cb[i] = (c < HID) ? b1[l * HID + c] : 0.f;
    } else {  // cnt zero
        int i = (b - 8608) * 256 + threadIdx.x;
        if (i < NN) cnt[i] = 0;
    }
}

// ---------------- h0 = sin(x@pw)*cos(x@pw) -> bf16 ----------------
__global__ __launch_bounds__(256) void proj_kernel(const float* __restrict__ x,
                                                   const float* __restrict__ pw,
                                                   bf16* __restrict__ hb) {
    int row = blockIdx.y;
    int col = blockIdx.x * 256 + threadIdx.x;
    __shared__ float xr[SDIM];
    if (threadIdx.x < SDIM) xr[threadIdx.x] = x[row * SDIM + threadIdx.x];
    __syncthreads();
    float acc = 0.f;
#pragma unroll
    for (int k = 0; k < SDIM; ++k) acc += xr[k] * pw[k * HID + col];
    hb[(size_t)row * HID + col] = (bf16)(sinf(acc) * cosf(acc));
}

// ---------------- 256x128 BK=32 triple-buffered counted-vmcnt MFMA GEMM ----------------
// R5/R8-verified (57.5 us @ CB shape). 8 waves (4M x 2N), 512 threads.
// LDS 72 KiB -> 2 blocks/CU. vmcnt(3) counted waits, compile-time mod-3
// buffers, T2 seg-XOR both-sides swizzle, GROUP-8 block swizzle.
template <int RELU, int HAS_BIAS, int HAS_RS, int WF32, int WB16>
__global__ __launch_bounds__(512, 4) void mgemm3_kernel(const bf16* __restrict__ A,
                                                        const bf16* __restrict__ Bt,
                                                        float* __restrict__ C,
                                                        bf16* __restrict__ Cb,
                                                        const float* __restrict__ bias,
                                                        const float* __restrict__ rowscale,
                                                        int M, int N, int K) {
    __shared__ bf16 lds[36864];  // 72 KiB
    const int tid = threadIdx.x;
    const int wave = tid >> 6, lane = tid & 63;
    const int wm = wave >> 1, wn = wave & 1;  // 4M x 2N
    const int quad = lane >> 4, r15 = lane & 15;

    const int num_n = gridDim.x, num_m = gridDim.y;
    int bid = blockIdx.x + blockIdx.y * num_n;
    const int GROUP = 8;
    int width = GROUP * num_n;
    int group = bid / width;
    int rem = bid - group * width;
    int rows_ing = num_m - group * GROUP;
    rows_ing = rows_ing < GROUP ? rows_ing : GROUP;
    int by = group * GROUP + rem % rows_ing;
    int bx = rem / rows_ing;
    const int m0 = by * 256, n0 = bx * 128;

    const int strow = tid >> 2;  // 0..127
    const int segsw = ((tid & 3) ^ ((tid >> 3) & 3)) * 8;
    int ar0 = m0 + strow;        ar0 = ar0 < M ? ar0 : M - 1;
    int ar1 = m0 + 128 + strow;  ar1 = ar1 < M ? ar1 : M - 1;
    const bf16* ga0 = A + (size_t)ar0 * K + segsw;
    const bf16* ga1 = A + (size_t)ar1 * K + segsw;
    const bf16* gb  = Bt + (size_t)(n0 + strow) * K + segsw;
    const int ldst = (tid & ~63) * 8;

    int aoff[4], boff[4];
#pragma unroll
    for (int i = 0; i < 4; ++i) {
        int rA = wm * 64 + i * 16 + r15;
        aoff[i] = 12288 + rA * 32 + (quad ^ ((rA >> 1) & 3)) * 8;
        int rB = wn * 64 + i * 16 + r15;
        boff[i] = rB * 32 + (quad ^ ((rB >> 1) & 3)) * 8;
    }

    f32x4 acc[4][4] = {};

#define STAGE3(bs, kt)                                                                                \
    do {                                                                                              \
        const int ko_ = (kt) << 5;                                                                    \
        __builtin_amdgcn_global_load_lds(AS1C(ga0 + ko_), AS3(&lds[12288 + (bs)*8192 + ldst]), 16, 0, 0); \
        __builtin_amdgcn_global_load_lds(AS1C(ga1 + ko_), AS3(&lds[12288 + (bs)*8192 + 4096 + ldst]), 16, 0, 0); \
        __builtin_amdgcn_global_load_lds(AS1C(gb + ko_), AS3(&lds[(bs)*4096 + ldst]), 16, 0, 0);      \
    } while (0)

    STAGE3(0, 0);
    STAGE3(1, 1);
    asm volatile("s_waitcnt vmcnt(3)");
    __builtin_amdgcn_s_barrier();

    const int NT = K >> 5;
    int t = 0;

#define TILE3(bi, bs)                                                                          \
    do {                                                                                       \
        int kt = (t + 2 < NT) ? (t + 2) : (t - 1);                                             \
        bf16x8 aF[4], bF[4];                                                                   \
        _Pragma("unroll") for (int i = 0; i < 4; ++i)                                          \
            aF[i] = *(const bf16x8*)(&lds[(bi)*8192 + aoff[i]]);                               \
        _Pragma("unroll") for (int j = 0; j < 4; ++j)                                          \
            bF[j] = *(const bf16x8*)(&lds[(bi)*4096 + boff[j]]);                               \
        STAGE3(bs, kt);                                                                        \
        asm volatile("s_waitcnt lgkmcnt(0)");                                                  \
        __builtin_amdgcn_s_setprio(1);                                                         \
        _Pragma("unroll") for (int i = 0; i < 4; ++i)                                          \
            _Pragma("unroll") for (int j = 0; j < 4; ++j)                                      \
                acc[i][j] = __builtin_amdgcn_mfma_f32_16x16x32_bf16(aF[i], bF[j], acc[i][j], 0, 0, 0); \
        __builtin_amdgcn_s_setprio(0);                                                         \
        asm volatile("s_waitcnt vmcnt(3)");                                                    \
        __builtin_amdgcn_s_barrier();                                                          \
        ++t;                                                                                   \
    } while (0)

    while (t + 3 <= NT) { TILE3(0, 2); TILE3(1, 0); TILE3(2, 1); }
    if (t < NT) TILE3(0, 2);
    if (t < NT) TILE3(1, 0);
#undef TILE3
#undef STAGE3

#pragma unroll
    for (int i = 0; i < 4; ++i) {
#pragma unroll
        for (int r = 0; r < 4; ++r) {
            int grow = m0 + wm * 64 + i * 16 + quad * 4 + r;
            if (grow >= M) continue;
            float rs = HAS_RS ? rowscale[grow] : 1.f;
#pragma unroll
            for (int j = 0; j < 4; ++j) {
                int gcol = n0 + wn * 64 + j * 16 + r15;
                float v = acc[i][j][r];
                if (HAS_BIAS) v += rs * bias[gcol];
                if (RELU) v = fmaxf(v, 0.f);
                if (WF32) C[(size_t)grow * N + gcol] = v;
                if (WB16) Cb[(size_t)grow * N + gcol] = (bf16)v;
            }
        }
    }
}

// ---------------- 128x128 BK=32 triple-buffered counted-vmcnt MFMA GEMM ----------------
// R7-verified. 4 waves, 256 threads, LDS 48 KiB -> 3 blocks/CU. For W2/ghost
// (sub-single-wave regime where occupancy beats intensity).
template <int RELU, int HAS_BIAS, int HAS_RS, int WF32, int WB16>
__global__ __launch_bounds__(256, 3) void mgemm3h_kernel(const bf16* __restrict__ A,
                                                         const bf16* __restrict__ Bt,
                                                         float* __restrict__ C,
                                                         bf16* __restrict__ Cb,
                                                         const float* __restrict__ bias,
                                                         const float* __restrict__ rowscale,
                                                         int M, int N, int K) {
    __shared__ bf16 lds[24576];  // 48 KiB
    const int tid = threadIdx.x;
    const int wave = tid >> 6, lane = tid & 63;
    const int wm = wave >> 1, wn = wave & 1;  // 2M x 2N
    const int quad = lane >> 4, r15 = lane & 15;

    const int num_n = gridDim.x, num_m = gridDim.y;
    int bid = blockIdx.x + blockIdx.y * num_n;
    const int GROUP = 8;
    int width = GROUP * num_n;
    int group = bid / width;
    int rem = bid - group * width;
    int rows_ing = num_m - group * GROUP;
    rows_ing = rows_ing < GROUP ? rows_ing : GROUP;
    int by = group * GROUP + rem % rows_ing;
    int bx = rem / rows_ing;
    const int m0 = by * 128, n0 = bx * 128;

    const int strow = tid >> 2;  // 0..63
    const int segsw = ((tid & 3) ^ ((tid >> 3) & 3)) * 8;
    int ar0 = m0 + strow;       ar0 = ar0 < M ? ar0 : M - 1;
    int ar1 = m0 + 64 + strow;  ar1 = ar1 < M ? ar1 : M - 1;
    const bf16* ga0 = A + (size_t)ar0 * K + segsw;
    const bf16* ga1 = A + (size_t)ar1 * K + segsw;
    const bf16* gb0 = Bt + (size_t)(n0 + strow) * K + segsw;
    const bf16* gb1 = Bt + (size_t)(n0 + 64 + strow) * K + segsw;
    const int ldst = (tid & ~63) * 8;

    int aoff[4], boff[4];
#pragma unroll
    for (int i = 0; i < 4; ++i) {
        int rA = wm * 64 + i * 16 + r15;
        aoff[i] = 12288 + rA * 32 + (quad ^ ((rA >> 1) & 3)) * 8;
        int rB = wn * 64 + i * 16 + r15;
        boff[i] = rB * 32 + (quad ^ ((rB >> 1) & 3)) * 8;
    }

    f32x4 acc[4][4] = {};

#define STAGE3H(bs, kt)                                                                                  \
    do {                                                                                                 \
        const int ko_ = (kt) << 5;                                                                       \
        __builtin_amdgcn_global_load_lds(AS1C(ga0 + ko_), AS3(&lds[12288 + (bs)*4096 + ldst]), 16, 0, 0); \
        __builtin_amdgcn_global_load_lds(AS1C(ga1 + ko_), AS3(&lds[12288 + (bs)*4096 + 2048 + ldst]), 16, 0, 0); \
        __builtin_amdgcn_global_load_lds(AS1C(gb0 + ko_), AS3(&lds[(bs)*4096 + ldst]), 16, 0, 0);        \
        __builtin_amdgcn_global_load_lds(AS1C(gb1 + ko_), AS3(&lds[(bs)*4096 + 2048 + ldst]), 16, 0, 0); \
    } while (0)

    STAGE3H(0, 0);
    STAGE3H(1, 1);
    asm volatile("s_waitcnt vmcnt(4)");
    __builtin_amdgcn_s_barrier();

    const int NT = K >> 5;
    int t = 0;

#define TILE3H(bi, bs)                                                                         \
    do {                                                                                       \
        int kt = (t + 2 < NT) ? (t + 2) : (t - 1);                                             \
        bf16x8 aF[4], bF[4];                                                                   \
        _Pragma("unroll") for (int i = 0; i < 4; ++i)                                          \
            aF[i] = *(const bf16x8*)(&lds[(bi)*4096 + aoff[i]]);                               \
        _Pragma("unroll") for (int j = 0; j < 4; ++j)                                          \
            bF[j] = *(const bf16x8*)(&lds[(bi)*4096 + boff[j]]);                               \
        STAGE3H(bs, kt);                                                                       \
        asm volatile("s_waitcnt lgkmcnt(0)");                                                  \
        __builtin_amdgcn_s_setprio(1);                                                         \
        _Pragma("unroll") for (int i = 0; i < 4; ++i)                                          \
            _Pragma("unroll") for (int j = 0; j < 4; ++j)                                      \
                acc[i][j] = __builtin_amdgcn_mfma_f32_16x16x32_bf16(aF[i], bF[j], acc[i][j], 0, 0, 0); \
        __builtin_amdgcn_s_setprio(0);                                                         \
        asm volatile("s_waitcnt vmcnt(4)");                                                    \
        __builtin_amdgcn_s_barrier();                                                          \
        ++t;                                                                                   \
    } while (0)

    while (t + 3 <= NT) { TILE3H(0, 2); TILE3H(1, 0); TILE3H(2, 1); }
    if (t < NT) TILE3H(0, 2);
    if (t < NT) TILE3H(1, 0);
#undef TILE3H
#undef STAGE3H

#pragma unroll
    for (int i = 0; i < 4; ++i) {
#pragma unroll
        for (int r = 0; r < 4; ++r) {
            int grow = m0 + wm * 64 + i * 16 + quad * 4 + r;
            if (grow >= M) continue;
            float rs = HAS_RS ? rowscale[grow] : 1.f;
#pragma unroll
            for (int j = 0; j < 4; ++j) {
                int gcol = n0 + wn * 64 + j * 16 + r15;
                float v = acc[i][j][r];
                if (HAS_BIAS) v += rs * bias[gcol];
                if (RELU) v = fmaxf(v, 0.f);
                if (WF32) C[(size_t)grow * N + gcol] = v;
                if (WB16) Cb[(size_t)grow * N + gcol] = (bf16)v;
            }
        }
    }
}

// ---------------- CSR aggregation over CB[node][2048] = [Cn ; Bn] ----------------
// R8 layout (2 nodes/block, 128-lane full-row coalesced reads) + edge-loop
// unroll x2: both 2KB row loads issued before either FMA chain (2x MLP).
// If gather is issue/latency-limited this is up to 2x on the loop; if
// fabric/L3-BW-bound it is exactly neutral (same bytes, same layout).
__global__ __launch_bounds__(256) void gather_kernel(const int* __restrict__ offs,
                                                     const int* __restrict__ esrc,
                                                     const bf16* __restrict__ CB,
                                                     bf16* __restrict__ Sb) {
    int half = threadIdx.x >> 7;
    int t = threadIdx.x & 127;
    int node = blockIdx.x * 2 + half;
    int c = t * 8;
    int k0 = offs[node], k1 = offs[node + 1];
    bf16x8 cv = *(const bf16x8*)(CB + (size_t)node * 2048 + c);
    float cf[8], a[8];
#pragma unroll
    for (int i = 0; i < 8; ++i) { cf[i] = (float)cv[i]; a[i] = 0.f; }
    int k = k0;
    for (; k + 2 <= k1; k += 2) {
        int s0 = esrc[k], s1 = esrc[k + 1];
        bf16x8 b0 = *(const bf16x8*)(CB + (size_t)s0 * 2048 + 1024 + c);
        bf16x8 b1 = *(const bf16x8*)(CB + (size_t)s1 * 2048 + 1024 + c);
#pragma unroll
        for (int i = 0; i < 8; ++i)
            a[i] += fmaxf(cf[i] + (float)b0[i], 0.f) + fmaxf(cf[i] + (float)b1[i], 0.f);
    }
    if (k < k1) {
        int s = esrc[k];
        bf16x8 bv = *(const bf16x8*)(CB + (size_t)s * 2048 + 1024 + c);
#pragma unroll
        for (int i = 0; i < 8; ++i) a[i] += fmaxf(cf[i] + (float)bv[i], 0.f);
    }
    bf16x8 o;
#pragma unroll
    for (int i = 0; i < 8; ++i) o[i] = (bf16)a[i];
    *(bf16x8*)(Sb + (size_t)node * HID + c) = o;
}

// ---------------- stable head via MFMA ----------------
__global__ __launch_bounds__(64) void stable_mfma_kernel(const bf16* __restrict__ hb,
                                                         const bf16* __restrict__ swt,
                                                         const float* __restrict__ sb,
                                                         float* __restrict__ out) {
    int m0 = blockIdx.x * 16;  // NN = 625*16 exact
    int lane = threadIdx.x;
    int quad = lane >> 4, r15 = lane & 15;
    f32x4 acc0 = {}, acc1 = {};
    const bf16* arow = hb + (size_t)(m0 + r15) * HID + quad * 8;
    const bf16* b0 = swt + (size_t)r15 * HID + quad * 8;
    const bf16* b1p = swt + (size_t)(16 + r15) * HID + quad * 8;
    for (int k0 = 0; k0 < HID; k0 += 32) {
        bf16x8 af = *(const bf16x8*)(arow + k0);
        bf16x8 bf0 = *(const bf16x8*)(b0 + k0);
        bf16x8 bf1 = *(const bf16x8*)(b1p + k0);
        acc0 = __builtin_amdgcn_mfma_f32_16x16x32_bf16(af, bf0, acc0, 0, 0, 0);
        acc1 = __builtin_amdgcn_mfma_f32_16x16x32_bf16(af, bf1, acc1, 0, 0, 0);
    }
#pragma unroll
    for (int r = 0; r < 4; ++r) {
        int grow = m0 + quad * 4 + r;
        out[(size_t)grow * SDIM + r15] = acc0[r] + sb[r15];
        if (r15 < 2) out[(size_t)grow * SDIM + 16 + r15] = acc1[r] + sb[16 + r15];
    }
}

// ---------------- ghost head stage 2 ----------------
__global__ __launch_bounds__(256) void ghost_kernel(const float* __restrict__ g1,
                                                    const float* __restrict__ gw2,
                                                    const float* __restrict__ gb2,
                                                    float* __restrict__ out) {
    int w = threadIdx.x >> 6, lane = threadIdx.x & 63;
    int row = blockIdx.x * 4 + w;  // NN = 2500*4 exact
    const float4 gv = *(const float4*)(g1 + (size_t)row * GHID + lane * 4);
    const float4 wv = *(const float4*)(gw2 + lane * 4);
    float v = gv.x * wv.x + gv.y * wv.y + gv.z * wv.z + gv.w * wv.w;
#pragma unroll
    for (int o = 32; o > 0; o >>= 1) v += __shfl_down(v, o, 64);
    if (lane == 0) out[row] = 1.f / (1.f + expf(-(v + gb2[0])));
}

extern "C" void kernel_launch(void* const* d_in, const int* in_sizes, int n_in,
                              void* d_out, int out_size, void* d_ws, size_t ws_size,
                              hipStream_t stream) {
    const float* x   = (const float*)d_in[0];
    const int*   ei  = (const int*)d_in[1];
    const float* pw  = (const float*)d_in[2];
    const float* W1  = (const float*)d_in[3];
    const float* b1  = (const float*)d_in[4];
    const float* W2  = (const float*)d_in[5];
    const float* b2  = (const float*)d_in[6];
    const float* gw1 = (const float*)d_in[7];
    const float* gb1 = (const float*)d_in[8];
    const float* gw2 = (const float*)d_in[9];
    const float* gb2 = (const float*)d_in[10];
    const float* sw  = (const float*)d_in[11];
    const float* sb  = (const float*)d_in[12];

    float* out    = (float*)d_out;
    float* ghost  = out;                  // [N,1]
    float* stable = out + NN;             // [N,18]
    float* h      = out + NN + NN * SDIM; // [N,HID] fp32 (final h output)

    const size_t H2 = (size_t)HID * HID;
    float* ws   = (float*)d_ws;
    float* g1   = ws;                                  // NN*GHID fp32
    float* degF = g1 + (size_t)NN * GHID;              // NN
    float* cb   = degF + NN;                           // 4*2048 fp32
    bf16* hb    = (bf16*)(cb + 4 * 2048);              // NN*HID
    bf16* Sb    = hb + (size_t)NN * HID;               // NN*HID
    bf16* CB    = Sb + (size_t)NN * HID;               // NN*2048
    bf16* WT    = CB + (size_t)NN * 2048;              // 4 * 2*H2  ([Wd;Wb]^T per layer)
    bf16* W2t   = WT + 8 * H2;                         // 4*H2
    bf16* gw1t  = W2t + 4 * H2;                        // GHID*HID
    bf16* swt   = gw1t + (size_t)GHID * HID;           // 32*1024
    int*  cnt    = (int*)(swt + 32 * 1024);
    int*  offs   = cnt + NN;
    int*  cursor = offs + NN + 1;
    int*  esrc   = cursor + NN;

    // ---- fused prep (weights transpose/convert + swt + cb + cnt zero) ----
    prep_kernel<<<dim3(8648), 256, 0, stream>>>(W1, W2, gw1, sw, b1, WT, W2t, gw1t, swt, cb, cnt);

    // ---- CSR build ----
    count_kernel<<<dim3((EE + 255) / 256), 256, 0, stream>>>(ei, cnt);
    scan_kernel<<<dim3(1), 256, 0, stream>>>(cnt, offs, cursor, degF);
    scatter_kernel<<<dim3((EE + 255) / 256), 256, 0, stream>>>(ei, cursor, esrc);

    // ---- h0 ----
    proj_kernel<<<dim3(HID / 256, NN), 256, 0, stream>>>(x, pw, hb);

    dim3 gcbg(2048 / 128, (NN + 255) / 256);     // (16, 40) = 640 blocks @ 256x128
    dim3 gw2grid(HID / 128, (NN + 127) / 128);   // (8, 79)  = 632 blocks @ 128x128
    for (int l = 0; l < NLAYERS; ++l) {
        // CB = hb @ [Wd ; Wb]^T + [b1 ; 0]   (N = 2048, fused Cn/Bn)
        mgemm3_kernel<0, 1, 0, 0, 1><<<gcbg, 512, 0, stream>>>(
            hb, WT + (size_t)l * 2 * H2, nullptr, CB, cb + l * 2048, nullptr, NN, 2048, HID);
        // S = segment_sum(relu(Cn[dst]+Bn[src]))
        gather_kernel<<<dim3(NN / 2), 256, 0, stream>>>(offs, esrc, CB, Sb);
        // h = relu(S @ W2 + deg*b2); last layer also writes fp32 h to d_out
        if (l < NLAYERS - 1)
            mgemm3h_kernel<1, 1, 1, 0, 1><<<gw2grid, 256, 0, stream>>>(
                Sb, W2t + (size_t)l * H2, nullptr, hb, b2 + (size_t)l * HID, degF, NN, HID, HID);
        else
            mgemm3h_kernel<1, 1, 1, 1, 1><<<gw2grid, 256, 0, stream>>>(
                Sb, W2t + (size_t)l * H2, h, hb, b2 + (size_t)l * HID, degF, NN, HID, HID);
    }

    // ---- ghost head (N=256, 158 blocks @ 128x128) ----
    mgemm3h_kernel<1, 1, 0, 1, 0><<<dim3(GHID / 128, (NN + 127) / 128), 256, 0, stream>>>(
        hb, gw1t, g1, nullptr, gb1, nullptr, NN, GHID, HID);
    ghost_kernel<<<dim3(NN / 4), 256, 0, stream>>>(g1, gw2, gb2, ghost);
    // ---- stable head (MFMA, 1 wave / 16 rows) ----
    stable_mfma_kernel<<<dim3(NN / 16), 64, 0, stream>>>(hb, swt, sb, stable);
}

// Round 12
// 686.849 us; speedup vs baseline: 1.1035x; 1.0042x over previous
//
#include <hip/hip_runtime.h>
#include <hip/hip_bf16.h>
#include <math.h>

#define NN 10000
#define EE 80000
#define SDIM 18
#define HID 1024
#define NLAYERS 4
#define GHID 256

typedef __bf16 bf16;
typedef __bf16 bf16x8 __attribute__((ext_vector_type(8)));
typedef __bf16 bf16x4 __attribute__((ext_vector_type(4)));
typedef float f32x4 __attribute__((ext_vector_type(4)));

#define AS1C(p) ((const __attribute__((address_space(1))) void*)(p))
#define AS3(p)  ((__attribute__((address_space(3))) void*)(p))

// ---------------- CSR build: count ----------------
__global__ void count_kernel(const int* __restrict__ ei, int* __restrict__ cnt) {
    int e = blockIdx.x * 256 + threadIdx.x;
    if (e < EE) atomicAdd(&cnt[ei[EE + e]], 1);
}

// ---------------- CSR build: exclusive scan (single block) ----------------
__global__ __launch_bounds__(256) void scan_kernel(const int* __restrict__ cnt,
                                                   int* __restrict__ offs,
                                                   int* __restrict__ cursor,
                                                   float* __restrict__ degF) {
    const int CH = 40;  // 256*40 = 10240 >= NN
    __shared__ int partial[256];
    int t = threadIdx.x;
    int base = t * CH;
    int local[CH];
    int sum = 0;
#pragma unroll
    for (int i = 0; i < CH; ++i) {
        int idx = base + i;
        int v = (idx < NN) ? cnt[idx] : 0;
        local[i] = sum;
        sum += v;
    }
    partial[t] = sum;
    __syncthreads();
    for (int off = 1; off < 256; off <<= 1) {
        int v = (t >= off) ? partial[t - off] : 0;
        __syncthreads();
        partial[t] += v;
        __syncthreads();
    }
    int excl = (t == 0) ? 0 : partial[t - 1];
#pragma unroll
    for (int i = 0; i < CH; ++i) {
        int idx = base + i;
        if (idx < NN) {
            int o = excl + local[i];
            offs[idx] = o;
            cursor[idx] = o;
            degF[idx] = (float)cnt[idx];
        }
    }
    if (t == 255) offs[NN] = partial[255];
}

// ---------------- CSR build: scatter edge sources ----------------
__global__ void scatter_kernel(const int* __restrict__ ei, int* __restrict__ cursor,
                               int* __restrict__ esrc) {
    int e = blockIdx.x * 256 + threadIdx.x;
    if (e < EE) {
        int dst = ei[EE + e];
        int pos = atomicAdd(&cursor[dst], 1);
        esrc[pos] = ei[e];
    }
}

// ---------------- fused prep: all weight transposes + swt + cb + cnt-zero ----------------
__global__ __launch_bounds__(256) void prep_kernel(const float* __restrict__ W1,
                                                   const float* __restrict__ W2,
                                                   const float* __restrict__ gw1,
                                                   const float* __restrict__ sw,
                                                   const float* __restrict__ b1,
                                                   bf16* __restrict__ WT,
                                                   bf16* __restrict__ W2t,
                                                   bf16* __restrict__ gw1t,
                                                   bf16* __restrict__ swt,
                                                   float* __restrict__ cb,
                                                   int* __restrict__ cnt) {
    __shared__ float td[32][33];
    __shared__ float tb[32][33];
    const size_t H2 = (size_t)HID * HID;
    int b = blockIdx.x;
    int tx = threadIdx.x & 31, ty = threadIdx.x >> 5;  // (32,8)

    if (b < 4096) {  // W1 fused diff transpose
        int l = b >> 10, r = b & 1023;
        int bx = (r & 31) * 32, by = (r >> 5) * 32;
        const float* s = W1 + (size_t)l * 2 * H2;
        bf16* d = WT + (size_t)l * 2 * H2;
#pragma unroll
        for (int r4 = 0; r4 < 4; ++r4) {
            int row = by + ty + r4 * 8;
            float vt = s[(size_t)row * HID + bx + tx];
            float vb = s[H2 + (size_t)row * HID + bx + tx];
            td[ty + r4 * 8][tx] = vt - vb;
            tb[ty + r4 * 8][tx] = vb;
        }
        __syncthreads();
#pragma unroll
        for (int r4 = 0; r4 < 4; ++r4) {
            int orow = bx + ty + r4 * 8;
            d[(size_t)orow * HID + by + tx] = (bf16)td[tx][ty + r4 * 8];
            d[(size_t)(HID + orow) * HID + by + tx] = (bf16)tb[tx][ty + r4 * 8];
        }
    } else if (b < 8192) {  // W2 transpose
        int sub = b - 4096;
        int l = sub >> 10, r = sub & 1023;
        int bx = (r & 31) * 32, by = (r >> 5) * 32;
        const float* s = W2 + (size_t)l * H2;
        bf16* d = W2t + (size_t)l * H2;
#pragma unroll
        for (int r4 = 0; r4 < 4; ++r4) {
            int row = by + ty + r4 * 8;
            td[ty + r4 * 8][tx] = s[(size_t)row * HID + bx + tx];
        }
        __syncthreads();
#pragma unroll
        for (int r4 = 0; r4 < 4; ++r4) {
            int orow = bx + ty + r4 * 8;
            d[(size_t)orow * HID + by + tx] = (bf16)td[tx][ty + r4 * 8];
        }
    } else if (b < 8448) {  // gw1 [1024][256] -> gw1t [256][1024]
        int sub = b - 8192;
        int bx = (sub & 7) * 32, by = (sub >> 3) * 32;
#pragma unroll
        for (int r4 = 0; r4 < 4; ++r4) {
            int row = by + ty + r4 * 8;
            td[ty + r4 * 8][tx] = gw1[(size_t)row * GHID + bx + tx];
        }
        __syncthreads();
#pragma unroll
        for (int r4 = 0; r4 < 4; ++r4) {
            int orow = bx + ty + r4 * 8;
            gw1t[(size_t)orow * HID + by + tx] = (bf16)td[tx][ty + r4 * 8];
        }
    } else if (b < 8576) {  // swt[32][1024] = sw[1024][18]^T zero-padded
        int i = (b - 8448) * 256 + threadIdx.x;
        int n = i >> 10, k = i & 1023;
        swt[i] = (bf16)(n < SDIM ? sw[k * SDIM + n] : 0.f);
    } else if (b < 8608) {  // cb[l][2048] = [b1[l] ; 0]
        int i = (b - 8576) * 256 + threadIdx.x;
        int l = i >> 11, c = i & 2047;
        cb[i] = (c < HID) ? b1[l * HID + c] : 0.f;
    } else {  // cnt zero
        int i = (b - 8608) * 256 + threadIdx.x;
        if (i < NN) cnt[i] = 0;
    }
}

// ---------------- h0 = sin(x@pw)*cos(x@pw) -> bf16 ----------------
__global__ __launch_bounds__(256) void proj_kernel(const float* __restrict__ x,
                                                   const float* __restrict__ pw,
                                                   bf16* __restrict__ hb) {
    int row = blockIdx.y;
    int col = blockIdx.x * 256 + threadIdx.x;
    __shared__ float xr[SDIM];
    if (threadIdx.x < SDIM) xr[threadIdx.x] = x[row * SDIM + threadIdx.x];
    __syncthreads();
    float acc = 0.f;
#pragma unroll
    for (int k = 0; k < SDIM; ++k) acc += xr[k] * pw[k * HID + col];
    hb[(size_t)row * HID + col] = (bf16)(sinf(acc) * cosf(acc));
}

// ---------------- 256x128 BK=32 triple-buffered counted-vmcnt MFMA GEMM ----------------
// R5/R8-verified (57.5 us @ CB shape). 8 waves (4M x 2N), 512 threads.
// LDS 72 KiB -> 2 blocks/CU. vmcnt(3) counted waits, compile-time mod-3
// buffers, T2 seg-XOR both-sides swizzle, GROUP-8 block swizzle.
template <int RELU, int HAS_BIAS, int HAS_RS, int WF32, int WB16>
__global__ __launch_bounds__(512, 4) void mgemm3_kernel(const bf16* __restrict__ A,
                                                        const bf16* __restrict__ Bt,
                                                        float* __restrict__ C,
                                                        bf16* __restrict__ Cb,
                                                        const float* __restrict__ bias,
                                                        const float* __restrict__ rowscale,
                                                        int M, int N, int K) {
    __shared__ bf16 lds[36864];  // 72 KiB
    const int tid = threadIdx.x;
    const int wave = tid >> 6, lane = tid & 63;
    const int wm = wave >> 1, wn = wave & 1;  // 4M x 2N
    const int quad = lane >> 4, r15 = lane & 15;

    const int num_n = gridDim.x, num_m = gridDim.y;
    int bid = blockIdx.x + blockIdx.y * num_n;
    const int GROUP = 8;
    int width = GROUP * num_n;
    int group = bid / width;
    int rem = bid - group * width;
    int rows_ing = num_m - group * GROUP;
    rows_ing = rows_ing < GROUP ? rows_ing : GROUP;
    int by = group * GROUP + rem % rows_ing;
    int bx = rem / rows_ing;
    const int m0 = by * 256, n0 = bx * 128;

    const int strow = tid >> 2;  // 0..127
    const int segsw = ((tid & 3) ^ ((tid >> 3) & 3)) * 8;
    int ar0 = m0 + strow;        ar0 = ar0 < M ? ar0 : M - 1;
    int ar1 = m0 + 128 + strow;  ar1 = ar1 < M ? ar1 : M - 1;
    const bf16* ga0 = A + (size_t)ar0 * K + segsw;
    const bf16* ga1 = A + (size_t)ar1 * K + segsw;
    const bf16* gb  = Bt + (size_t)(n0 + strow) * K + segsw;
    const int ldst = (tid & ~63) * 8;

    int aoff[4], boff[4];
#pragma unroll
    for (int i = 0; i < 4; ++i) {
        int rA = wm * 64 + i * 16 + r15;
        aoff[i] = 12288 + rA * 32 + (quad ^ ((rA >> 1) & 3)) * 8;
        int rB = wn * 64 + i * 16 + r15;
        boff[i] = rB * 32 + (quad ^ ((rB >> 1) & 3)) * 8;
    }

    f32x4 acc[4][4] = {};

#define STAGE3(bs, kt)                                                                                \
    do {                                                                                              \
        const int ko_ = (kt) << 5;                                                                    \
        __builtin_amdgcn_global_load_lds(AS1C(ga0 + ko_), AS3(&lds[12288 + (bs)*8192 + ldst]), 16, 0, 0); \
        __builtin_amdgcn_global_load_lds(AS1C(ga1 + ko_), AS3(&lds[12288 + (bs)*8192 + 4096 + ldst]), 16, 0, 0); \
        __builtin_amdgcn_global_load_lds(AS1C(gb + ko_), AS3(&lds[(bs)*4096 + ldst]), 16, 0, 0);      \
    } while (0)

    STAGE3(0, 0);
    STAGE3(1, 1);
    asm volatile("s_waitcnt vmcnt(3)");
    __builtin_amdgcn_s_barrier();

    const int NT = K >> 5;
    int t = 0;

#define TILE3(bi, bs)                                                                          \
    do {                                                                                       \
        int kt = (t + 2 < NT) ? (t + 2) : (t - 1);                                             \
        bf16x8 aF[4], bF[4];                                                                   \
        _Pragma("unroll") for (int i = 0; i < 4; ++i)                                          \
            aF[i] = *(const bf16x8*)(&lds[(bi)*8192 + aoff[i]]);                               \
        _Pragma("unroll") for (int j = 0; j < 4; ++j)                                          \
            bF[j] = *(const bf16x8*)(&lds[(bi)*4096 + boff[j]]);                               \
        STAGE3(bs, kt);                                                                        \
        asm volatile("s_waitcnt lgkmcnt(0)");                                                  \
        __builtin_amdgcn_s_setprio(1);                                                         \
        _Pragma("unroll") for (int i = 0; i < 4; ++i)                                          \
            _Pragma("unroll") for (int j = 0; j < 4; ++j)                                      \
                acc[i][j] = __builtin_amdgcn_mfma_f32_16x16x32_bf16(aF[i], bF[j], acc[i][j], 0, 0, 0); \
        __builtin_amdgcn_s_setprio(0);                                                         \
        asm volatile("s_waitcnt vmcnt(3)");                                                    \
        __builtin_amdgcn_s_barrier();                                                          \
        ++t;                                                                                   \
    } while (0)

    while (t + 3 <= NT) { TILE3(0, 2); TILE3(1, 0); TILE3(2, 1); }
    if (t < NT) TILE3(0, 2);
    if (t < NT) TILE3(1, 0);
#undef TILE3
#undef STAGE3

#pragma unroll
    for (int i = 0; i < 4; ++i) {
#pragma unroll
        for (int r = 0; r < 4; ++r) {
            int grow = m0 + wm * 64 + i * 16 + quad * 4 + r;
            if (grow >= M) continue;
            float rs = HAS_RS ? rowscale[grow] : 1.f;
#pragma unroll
            for (int j = 0; j < 4; ++j) {
                int gcol = n0 + wn * 64 + j * 16 + r15;
                float v = acc[i][j][r];
                if (HAS_BIAS) v += rs * bias[gcol];
                if (RELU) v = fmaxf(v, 0.f);
                if (WF32) C[(size_t)grow * N + gcol] = v;
                if (WB16) Cb[(size_t)grow * N + gcol] = (bf16)v;
            }
        }
    }
}

// ---------------- 128x128 BK=32 triple-buffered counted-vmcnt MFMA GEMM ----------------
// R7-verified. 4 waves, 256 threads, LDS 48 KiB -> 3 blocks/CU. For W2/ghost
// (sub-single-wave regime where occupancy beats intensity).
template <int RELU, int HAS_BIAS, int HAS_RS, int WF32, int WB16>
__global__ __launch_bounds__(256, 3) void mgemm3h_kernel(const bf16* __restrict__ A,
                                                         const bf16* __restrict__ Bt,
                                                         float* __restrict__ C,
                                                         bf16* __restrict__ Cb,
                                                         const float* __restrict__ bias,
                                                         const float* __restrict__ rowscale,
                                                         int M, int N, int K) {
    __shared__ bf16 lds[24576];  // 48 KiB
    const int tid = threadIdx.x;
    const int wave = tid >> 6, lane = tid & 63;
    const int wm = wave >> 1, wn = wave & 1;  // 2M x 2N
    const int quad = lane >> 4, r15 = lane & 15;

    const int num_n = gridDim.x, num_m = gridDim.y;
    int bid = blockIdx.x + blockIdx.y * num_n;
    const int GROUP = 8;
    int width = GROUP * num_n;
    int group = bid / width;
    int rem = bid - group * width;
    int rows_ing = num_m - group * GROUP;
    rows_ing = rows_ing < GROUP ? rows_ing : GROUP;
    int by = group * GROUP + rem % rows_ing;
    int bx = rem / rows_ing;
    const int m0 = by * 128, n0 = bx * 128;

    const int strow = tid >> 2;  // 0..63
    const int segsw = ((tid & 3) ^ ((tid >> 3) & 3)) * 8;
    int ar0 = m0 + strow;       ar0 = ar0 < M ? ar0 : M - 1;
    int ar1 = m0 + 64 + strow;  ar1 = ar1 < M ? ar1 : M - 1;
    const bf16* ga0 = A + (size_t)ar0 * K + segsw;
    const bf16* ga1 = A + (size_t)ar1 * K + segsw;
    const bf16* gb0 = Bt + (size_t)(n0 + strow) * K + segsw;
    const bf16* gb1 = Bt + (size_t)(n0 + 64 + strow) * K + segsw;
    const int ldst = (tid & ~63) * 8;

    int aoff[4], boff[4];
#pragma unroll
    for (int i = 0; i < 4; ++i) {
        int rA = wm * 64 + i * 16 + r15;
        aoff[i] = 12288 + rA * 32 + (quad ^ ((rA >> 1) & 3)) * 8;
        int rB = wn * 64 + i * 16 + r15;
        boff[i] = rB * 32 + (quad ^ ((rB >> 1) & 3)) * 8;
    }

    f32x4 acc[4][4] = {};

#define STAGE3H(bs, kt)                                                                                  \
    do {                                                                                                 \
        const int ko_ = (kt) << 5;                                                                       \
        __builtin_amdgcn_global_load_lds(AS1C(ga0 + ko_), AS3(&lds[12288 + (bs)*4096 + ldst]), 16, 0, 0); \
        __builtin_amdgcn_global_load_lds(AS1C(ga1 + ko_), AS3(&lds[12288 + (bs)*4096 + 2048 + ldst]), 16, 0, 0); \
        __builtin_amdgcn_global_load_lds(AS1C(gb0 + ko_), AS3(&lds[(bs)*4096 + ldst]), 16, 0, 0);        \
        __builtin_amdgcn_global_load_lds(AS1C(gb1 + ko_), AS3(&lds[(bs)*4096 + 2048 + ldst]), 16, 0, 0); \
    } while (0)

    STAGE3H(0, 0);
    STAGE3H(1, 1);
    asm volatile("s_waitcnt vmcnt(4)");
    __builtin_amdgcn_s_barrier();

    const int NT = K >> 5;
    int t = 0;

#define TILE3H(bi, bs)                                                                         \
    do {                                                                                       \
        int kt = (t + 2 < NT) ? (t + 2) : (t - 1);                                             \
        bf16x8 aF[4], bF[4];                                                                   \
        _Pragma("unroll") for (int i = 0; i < 4; ++i)                                          \
            aF[i] = *(const bf16x8*)(&lds[(bi)*4096 + aoff[i]]);                               \
        _Pragma("unroll") for (int j = 0; j < 4; ++j)                                          \
            bF[j] = *(const bf16x8*)(&lds[(bi)*4096 + boff[j]]);                               \
        STAGE3H(bs, kt);                                                                       \
        asm volatile("s_waitcnt lgkmcnt(0)");                                                  \
        __builtin_amdgcn_s_setprio(1);                                                         \
        _Pragma("unroll") for (int i = 0; i < 4; ++i)                                          \
            _Pragma("unroll") for (int j = 0; j < 4; ++j)                                      \
                acc[i][j] = __builtin_amdgcn_mfma_f32_16x16x32_bf16(aF[i], bF[j], acc[i][j], 0, 0, 0); \
        __builtin_amdgcn_s_setprio(0);                                                         \
        asm volatile("s_waitcnt vmcnt(4)");                                                    \
        __builtin_amdgcn_s_barrier();                                                          \
        ++t;                                                                                   \
    } while (0)

    while (t + 3 <= NT) { TILE3H(0, 2); TILE3H(1, 0); TILE3H(2, 1); }
    if (t < NT) TILE3H(0, 2);
    if (t < NT) TILE3H(1, 0);
#undef TILE3H
#undef STAGE3H

#pragma unroll
    for (int i = 0; i < 4; ++i) {
#pragma unroll
        for (int r = 0; r < 4; ++r) {
            int grow = m0 + wm * 64 + i * 16 + quad * 4 + r;
            if (grow >= M) continue;
            float rs = HAS_RS ? rowscale[grow] : 1.f;
#pragma unroll
            for (int j = 0; j < 4; ++j) {
                int gcol = n0 + wn * 64 + j * 16 + r15;
                float v = acc[i][j][r];
                if (HAS_BIAS) v += rs * bias[gcol];
                if (RELU) v = fmaxf(v, 0.f);
                if (WF32) C[(size_t)grow * N + gcol] = v;
                if (WB16) Cb[(size_t)grow * N + gcol] = (bf16)v;
            }
        }
    }
}

// ---------------- CSR aggregation over CB[node][2048] = [Cn ; Bn] ----------------
// R8 layout (2 nodes/block, 128-lane full-row coalesced reads) + edge-loop
// unroll x4 (R11's x2 gave -5 us/call -> latency-bound confirmed; x4 targets
// the remaining ~15 us/call latency gap). All 4 row-loads issued before any
// FMA chain; node's esrc indices are contiguous (uniform broadcast loads).
__global__ __launch_bounds__(256) void gather_kernel(const int* __restrict__ offs,
                                                     const int* __restrict__ esrc,
                                                     const bf16* __restrict__ CB,
                                                     bf16* __restrict__ Sb) {
    int half = threadIdx.x >> 7;
    int t = threadIdx.x & 127;
    int node = blockIdx.x * 2 + half;
    int c = t * 8;
    int k0 = offs[node], k1 = offs[node + 1];
    bf16x8 cv = *(const bf16x8*)(CB + (size_t)node * 2048 + c);
    float cf[8], a[8];
#pragma unroll
    for (int i = 0; i < 8; ++i) { cf[i] = (float)cv[i]; a[i] = 0.f; }
    int k = k0;
    for (; k + 4 <= k1; k += 4) {
        int s0 = esrc[k], s1 = esrc[k + 1], s2 = esrc[k + 2], s3 = esrc[k + 3];
        bf16x8 b0 = *(const bf16x8*)(CB + (size_t)s0 * 2048 + 1024 + c);
        bf16x8 b1 = *(const bf16x8*)(CB + (size_t)s1 * 2048 + 1024 + c);
        bf16x8 b2 = *(const bf16x8*)(CB + (size_t)s2 * 2048 + 1024 + c);
        bf16x8 b3 = *(const bf16x8*)(CB + (size_t)s3 * 2048 + 1024 + c);
#pragma unroll
        for (int i = 0; i < 8; ++i)
            a[i] += (fmaxf(cf[i] + (float)b0[i], 0.f) + fmaxf(cf[i] + (float)b1[i], 0.f)) +
                    (fmaxf(cf[i] + (float)b2[i], 0.f) + fmaxf(cf[i] + (float)b3[i], 0.f));
    }
    if (k + 2 <= k1) {
        int s0 = esrc[k], s1 = esrc[k + 1];
        bf16x8 b0 = *(const bf16x8*)(CB + (size_t)s0 * 2048 + 1024 + c);
        bf16x8 b1 = *(const bf16x8*)(CB + (size_t)s1 * 2048 + 1024 + c);
#pragma unroll
        for (int i = 0; i < 8; ++i)
            a[i] += fmaxf(cf[i] + (float)b0[i], 0.f) + fmaxf(cf[i] + (float)b1[i], 0.f);
        k += 2;
    }
    if (k < k1) {
        int s = esrc[k];
        bf16x8 bv = *(const bf16x8*)(CB + (size_t)s * 2048 + 1024 + c);
#pragma unroll
        for (int i = 0; i < 8; ++i) a[i] += fmaxf(cf[i] + (float)bv[i], 0.f);
    }
    bf16x8 o;
#pragma unroll
    for (int i = 0; i < 8; ++i) o[i] = (bf16)a[i];
    *(bf16x8*)(Sb + (size_t)node * HID + c) = o;
}

// ---------------- stable head via MFMA ----------------
__global__ __launch_bounds__(64) void stable_mfma_kernel(const bf16* __restrict__ hb,
                                                         const bf16* __restrict__ swt,
                                                         const float* __restrict__ sb,
                                                         float* __restrict__ out) {
    int m0 = blockIdx.x * 16;  // NN = 625*16 exact
    int lane = threadIdx.x;
    int quad = lane >> 4, r15 = lane & 15;
    f32x4 acc0 = {}, acc1 = {};
    const bf16* arow = hb + (size_t)(m0 + r15) * HID + quad * 8;
    const bf16* b0 = swt + (size_t)r15 * HID + quad * 8;
    const bf16* b1p = swt + (size_t)(16 + r15) * HID + quad * 8;
    for (int k0 = 0; k0 < HID; k0 += 32) {
        bf16x8 af = *(const bf16x8*)(arow + k0);
        bf16x8 bf0 = *(const bf16x8*)(b0 + k0);
        bf16x8 bf1 = *(const bf16x8*)(b1p + k0);
        acc0 = __builtin_amdgcn_mfma_f32_16x16x32_bf16(af, bf0, acc0, 0, 0, 0);
        acc1 = __builtin_amdgcn_mfma_f32_16x16x32_bf16(af, bf1, acc1, 0, 0, 0);
    }
#pragma unroll
    for (int r = 0; r < 4; ++r) {
        int grow = m0 + quad * 4 + r;
        out[(size_t)grow * SDIM + r15] = acc0[r] + sb[r15];
        if (r15 < 2) out[(size_t)grow * SDIM + 16 + r15] = acc1[r] + sb[16 + r15];
    }
}

// ---------------- ghost head stage 2 ----------------
__global__ __launch_bounds__(256) void ghost_kernel(const float* __restrict__ g1,
                                                    const float* __restrict__ gw2,
                                                    const float* __restrict__ gb2,
                                                    float* __restrict__ out) {
    int w = threadIdx.x >> 6, lane = threadIdx.x & 63;
    int row = blockIdx.x * 4 + w;  // NN = 2500*4 exact
    const float4 gv = *(const float4*)(g1 + (size_t)row * GHID + lane * 4);
    const float4 wv = *(const float4*)(gw2 + lane * 4);
    float v = gv.x * wv.x + gv.y * wv.y + gv.z * wv.z + gv.w * wv.w;
#pragma unroll
    for (int o = 32; o > 0; o >>= 1) v += __shfl_down(v, o, 64);
    if (lane == 0) out[row] = 1.f / (1.f + expf(-(v + gb2[0])));
}

extern "C" void kernel_launch(void* const* d_in, const int* in_sizes, int n_in,
                              void* d_out, int out_size, void* d_ws, size_t ws_size,
                              hipStream_t stream) {
    const float* x   = (const float*)d_in[0];
    const int*   ei  = (const int*)d_in[1];
    const float* pw  = (const float*)d_in[2];
    const float* W1  = (const float*)d_in[3];
    const float* b1  = (const float*)d_in[4];
    const float* W2  = (const float*)d_in[5];
    const float* b2  = (const float*)d_in[6];
    const float* gw1 = (const float*)d_in[7];
    const float* gb1 = (const float*)d_in[8];
    const float* gw2 = (const float*)d_in[9];
    const float* gb2 = (const float*)d_in[10];
    const float* sw  = (const float*)d_in[11];
    const float* sb  = (const float*)d_in[12];

    float* out    = (float*)d_out;
    float* ghost  = out;                  // [N,1]
    float* stable = out + NN;             // [N,18]
    float* h      = out + NN + NN * SDIM; // [N,HID] fp32 (final h output)

    const size_t H2 = (size_t)HID * HID;
    float* ws   = (float*)d_ws;
    float* g1   = ws;                                  // NN*GHID fp32
    float* degF = g1 + (size_t)NN * GHID;              // NN
    float* cb   = degF + NN;                           // 4*2048 fp32
    bf16* hb    = (bf16*)(cb + 4 * 2048);              // NN*HID
    bf16* Sb    = hb + (size_t)NN * HID;               // NN*HID
    bf16* CB    = Sb + (size_t)NN * HID;               // NN*2048
    bf16* WT    = CB + (size_t)NN * 2048;              // 4 * 2*H2  ([Wd;Wb]^T per layer)
    bf16* W2t   = WT + 8 * H2;                         // 4*H2
    bf16* gw1t  = W2t + 4 * H2;                        // GHID*HID
    bf16* swt   = gw1t + (size_t)GHID * HID;           // 32*1024
    int*  cnt    = (int*)(swt + 32 * 1024);
    int*  offs   = cnt + NN;
    int*  cursor = offs + NN + 1;
    int*  esrc   = cursor + NN;

    // ---- fused prep (weights transpose/convert + swt + cb + cnt zero) ----
    prep_kernel<<<dim3(8648), 256, 0, stream>>>(W1, W2, gw1, sw, b1, WT, W2t, gw1t, swt, cb, cnt);

    // ---- CSR build ----
    count_kernel<<<dim3((EE + 255) / 256), 256, 0, stream>>>(ei, cnt);
    scan_kernel<<<dim3(1), 256, 0, stream>>>(cnt, offs, cursor, degF);
    scatter_kernel<<<dim3((EE + 255) / 256), 256, 0, stream>>>(ei, cursor, esrc);

    // ---- h0 ----
    proj_kernel<<<dim3(HID / 256, NN), 256, 0, stream>>>(x, pw, hb);

    dim3 gcbg(2048 / 128, (NN + 255) / 256);     // (16, 40) = 640 blocks @ 256x128
    dim3 gw2grid(HID / 128, (NN + 127) / 128);   // (8, 79)  = 632 blocks @ 128x128
    for (int l = 0; l < NLAYERS; ++l) {
        // CB = hb @ [Wd ; Wb]^T + [b1 ; 0]   (N = 2048, fused Cn/Bn)
        mgemm3_kernel<0, 1, 0, 0, 1><<<gcbg, 512, 0, stream>>>(
            hb, WT + (size_t)l * 2 * H2, nullptr, CB, cb + l * 2048, nullptr, NN, 2048, HID);
        // S = segment_sum(relu(Cn[dst]+Bn[src]))
        gather_kernel<<<dim3(NN / 2), 256, 0, stream>>>(offs, esrc, CB, Sb);
        // h = relu(S @ W2 + deg*b2); last layer also writes fp32 h to d_out
        if (l < NLAYERS - 1)
            mgemm3h_kernel<1, 1, 1, 0, 1><<<gw2grid, 256, 0, stream>>>(
                Sb, W2t + (size_t)l * H2, nullptr, hb, b2 + (size_t)l * HID, degF, NN, HID, HID);
        else
            mgemm3h_kernel<1, 1, 1, 1, 1><<<gw2grid, 256, 0, stream>>>(
                Sb, W2t + (size_t)l * H2, h, hb, b2 + (size_t)l * HID, degF, NN, HID, HID);
    }

    // ---- ghost head (N=256, 158 blocks @ 128x128) ----
    mgemm3h_kernel<1, 1, 0, 1, 0><<<dim3(GHID / 128, (NN + 127) / 128), 256, 0, stream>>>(
        hb, gw1t, g1, nullptr, gb1, nullptr, NN, GHID, HID);
    ghost_kernel<<<dim3(NN / 4), 256, 0, stream>>>(g1, gw2, gb2, ghost);
    // ---- stable head (MFMA, 1 wave / 16 rows) ----
    stable_mfma_kernel<<<dim3(NN / 16), 64, 0, stream>>>(hb, swt, sb, stable);
}